// Round 12
// baseline (180.432 us; speedup 1.0000x reference)
//
#include <hip/hip_runtime.h>

#define N 8192
#define D 256
#define BM 128                    // I-tile rows (per block)
#define BJ 64                     // J-tile rows (per jj step)
#define JG 8                      // J-tiles per block
#define GJ (N / BJ / JG)          // 16
#define GI (N / BM)               // 64
#define NPART (3 * GI * GJ)       // 3072 partials

typedef int   i32x8 __attribute__((ext_vector_type(8)));
typedef float f32x4 __attribute__((ext_vector_type(4)));
typedef float f32x2 __attribute__((ext_vector_type(2)));

// -------- prep: fp32 -> fp8 e4m3 (packed), norms of the DEQUANTIZED values ----
__device__ __forceinline__ unsigned pack_fp8x4(float a, float b, float c, float d) {
    unsigned lo = __builtin_amdgcn_cvt_pk_fp8_f32(a, b, 0, false);
    return __builtin_amdgcn_cvt_pk_fp8_f32(c, d, lo, true);
}
__device__ __forceinline__ float dequant_sumsq(unsigned q) {
    const float v0 = __builtin_amdgcn_cvt_f32_fp8(q, 0);
    const float v1 = __builtin_amdgcn_cvt_f32_fp8(q, 1);
    const float v2 = __builtin_amdgcn_cvt_f32_fp8(q, 2);
    const float v3 = __builtin_amdgcn_cvt_f32_fp8(q, 3);
    return fmaf(v0, v0, fmaf(v1, v1, fmaf(v2, v2, v3 * v3)));
}

__global__ void prep_kernel(const float* __restrict__ x1, const float* __restrict__ x2,
                            unsigned* __restrict__ x1q, unsigned* __restrict__ x2q,
                            unsigned* __restrict__ pq,
                            float* __restrict__ sq1, float* __restrict__ sq2,
                            float* __restrict__ sqp) {
    const int tid = threadIdx.x, lane = tid & 63, wv = tid >> 6;
    const int row = blockIdx.x * 4 + wv;
    const size_t eb = (size_t)row * D + lane * 4;
    const float4 a = *(const float4*)(x1 + eb);
    const float4 b = *(const float4*)(x2 + eb);
    const float px = 0.5f * (a.x + b.x), py = 0.5f * (a.y + b.y);
    const float pz = 0.5f * (a.z + b.z), pw = 0.5f * (a.w + b.w);
    const unsigned qa = pack_fp8x4(a.x, a.y, a.z, a.w);
    const unsigned qb = pack_fp8x4(b.x, b.y, b.z, b.w);
    const unsigned qp = pack_fp8x4(px, py, pz, pw);
    const size_t wb = (size_t)row * (D / 4) + lane;
    x1q[wb] = qa; x2q[wb] = qb; pq[wb] = qp;
    float s1 = dequant_sumsq(qa), s2 = dequant_sumsq(qb), sp = dequant_sumsq(qp);
    #pragma unroll
    for (int o = 32; o > 0; o >>= 1) {
        s1 += __shfl_down(s1, o, 64);
        s2 += __shfl_down(s2, o, 64);
        sp += __shfl_down(sp, o, 64);
    }
    if (lane == 0) { sq1[row] = s1; sq2[row] = s2; sqp[row] = sp; }
}

// -------- main ---------------------------------------------------------------
__device__ __forceinline__ f32x4 mfma8(i32x8 a, i32x8 b, f32x4 c) {
    return __builtin_amdgcn_mfma_scale_f32_16x16x128_f8f6f4(
        a, b, c, 0, 0, 0, 0x7F7F7F7F, 0, 0x7F7F7F7F);
}

// packed-f32 log-sum over 32 entries (4 ti x 2 tj x 4 regs); sa in registers
__device__ __forceinline__ float logsumP(const f32x4 (&acc)[4][2],
                                         const f32x2 (&sa01)[4], const f32x2 (&sa23)[4],
                                         const float sb[2]) {
    float s = 0.0f;
    #pragma unroll
    for (int ti = 0; ti < 4; ++ti) {
        f32x2 pr = {1.0f, 1.0f};
        #pragma unroll
        for (int tj = 0; tj < 2; ++tj) {
            const f32x2 sbv = {sb[tj], sb[tj]};
            const f32x2 t01 = sa01[ti] + sbv, t23 = sa23[ti] + sbv;
            const f32x2 v01 = {acc[ti][tj][0], acc[ti][tj][1]};
            const f32x2 v23 = {acc[ti][tj][2], acc[ti][tj][3]};
            f32x2 d01 = t01 - 2.0f * v01;
            f32x2 d23 = t23 - 2.0f * v23;
            d01 = __builtin_elementwise_max(d01, (f32x2){1.0f, 1.0f});
            d23 = __builtin_elementwise_max(d23, (f32x2){1.0f, 1.0f});
            pr *= d01; pr *= d23;
        }
        s += __logf(pr.x * pr.y);   // product of 8 dists <= (1.5e3)^8, fp32-safe
    }
    return s;
}

// diagonal-straddling tile: per-entry exponent 2 (j>i) / 1 (j==i) / 0 (j<i)
__device__ __forceinline__ float logsumStraddle(const f32x4 (&acc)[4][2],
                                                const f32x2 (&sa01)[4], const f32x2 (&sa23)[4],
                                                const float sb[2],
                                                int wr, int wc, int quad, int l15,
                                                int I0, int J0) {
    float s = 0.0f;
    #pragma unroll
    for (int ti = 0; ti < 4; ++ti) {
        #pragma unroll
        for (int tj = 0; tj < 2; ++tj) {
            const int j = J0 + wc * 32 + tj * 16 + l15;
            float pr = 1.0f;
            #pragma unroll
            for (int r = 0; r < 4; ++r) {
                const int i = I0 + wr * 64 + ti * 16 + quad * 4 + r;
                const float sav = (r < 2) ? ((r & 1) ? sa01[ti].y : sa01[ti].x)
                                          : ((r & 1) ? sa23[ti].y : sa23[ti].x);
                float d = fmaf(-2.0f, acc[ti][tj][r], sav + sb[tj]);
                d = fmaxf(d, 1.0f);
                const float t = (j > i) ? d : 1.0f;
                const float u = (j >= i) ? d : 1.0f;
                pr *= t * u;
            }
            s += __logf(pr);
        }
    }
    return s;
}

__global__ __launch_bounds__(256) void mqjs_main(
    const unsigned char* __restrict__ x1q, const unsigned char* __restrict__ x2q,
    const unsigned char* __restrict__ pq,
    const float* __restrict__ sq1, const float* __restrict__ sq2,
    const float* __restrict__ sqp, float* __restrict__ partials) {

    __shared__ float red[4];                  // only LDS use: final block reduce

    const int tid = threadIdx.x;
    const int lane = tid & 63;
    const int wv = tid >> 6;
    const int wr = wv >> 1, wc = wv & 1;      // wave: 64 I-rows x 32 J-cols
    const int quad = lane >> 4, l15 = lane & 15;

    const int z = blockIdx.z;
    const int I0 = blockIdx.y * BM;
    const int jbase = blockIdx.x * JG;
    const int pid = (z * GI + blockIdx.y) * GJ + blockIdx.x;
    const float wse = -(float)N / (float)(N - 1);

    int jj0 = 0;
    if (z == 2) {                              // first J-tile touching j >= i
        jj0 = 2 * (int)blockIdx.y - jbase;
        if (jj0 < 0) jj0 = 0;
        if (jj0 >= JG) { if (tid == 0) partials[pid] = 0.0f; return; }
    }

    const unsigned char* Ag = (z == 1) ? x2q : x1q;
    const unsigned char* Bg = (z == 2) ? x1q : pq;
    const float* sqAg = (z == 1) ? sq2 : sq1;
    const float* sqBg = (z == 2) ? sq1 : sqp;

    // A fragments + sqA straight from global (once per block; L2-resident)
    i32x8 af[2][4];
    f32x2 sa01[4], sa23[4];
    #pragma unroll
    for (int ti = 0; ti < 4; ++ti) {
        #pragma unroll
        for (int kc = 0; kc < 2; ++kc) {
            const size_t ro = (size_t)(I0 + wr * 64 + ti * 16 + l15) * D + kc * 128 + quad * 32;
            af[kc][ti] = *(const i32x8*)(Ag + ro);
        }
        const int sbase = I0 + wr * 64 + ti * 16 + quad * 4;
        sa01[ti] = (f32x2){sqAg[sbase], sqAg[sbase + 1]};
        sa23[ti] = (f32x2){sqAg[sbase + 2], sqAg[sbase + 3]};
    }

    float tsum = 0.0f;

    for (int jj = jj0; jj < JG; ++jj) {
        const int J0 = (jbase + jj) * BJ;

        // B fragments straight from global (quad-uniform addrs coalesce; L2/LLC-hot)
        i32x8 bfr[2][2];                       // [kc][tj]
        #pragma unroll
        for (int kc = 0; kc < 2; ++kc)
            #pragma unroll
            for (int tj = 0; tj < 2; ++tj)
                bfr[kc][tj] = *(const i32x8*)(Bg +
                    (size_t)(J0 + wc * 32 + tj * 16 + l15) * D + kc * 128 + quad * 32);

        float sb[2];
        #pragma unroll
        for (int tj = 0; tj < 2; ++tj) sb[tj] = sqBg[J0 + wc * 32 + tj * 16 + l15];

        f32x4 acc[4][2];
        #pragma unroll
        for (int a = 0; a < 4; ++a)
            #pragma unroll
            for (int b = 0; b < 2; ++b)
                acc[a][b] = (f32x4){0.f, 0.f, 0.f, 0.f};
        #pragma unroll
        for (int kc = 0; kc < 2; ++kc)
            #pragma unroll
            for (int ti = 0; ti < 4; ++ti)
                #pragma unroll
                for (int tj = 0; tj < 2; ++tj)
                    acc[ti][tj] = mfma8(af[kc][ti], bfr[kc][tj], acc[ti][tj]);

        if (z < 2) {
            tsum += 0.5f * logsumP(acc, sa01, sa23, sb);
        } else if (J0 >= I0 + BM) {
            tsum += wse * logsumP(acc, sa01, sa23, sb);          // upper full: 2 * 0.5 * wse
        } else {
            tsum += 0.5f * wse * logsumStraddle(acc, sa01, sa23, sb, wr, wc, quad, l15, I0, J0);
        }
    }

    #pragma unroll
    for (int o = 32; o > 0; o >>= 1) tsum += __shfl_down(tsum, o, 64);
    if (lane == 0) red[wv] = tsum;
    __syncthreads();
    if (tid == 0) partials[pid] = red[0] + red[1] + red[2] + red[3];
}

// reduce 3072 partials (double accumulation) -> final scalar
__global__ void finalize_kernel(const float* __restrict__ partials, float* __restrict__ out) {
    const int tid = threadIdx.x;              // 768 threads
    const float4 v = ((const float4*)partials)[tid];
    double s = (double)v.x + (double)v.y + (double)v.z + (double)v.w;
    #pragma unroll
    for (int o = 32; o > 0; o >>= 1) s += __shfl_down(s, o, 64);
    __shared__ double r[12];
    if ((tid & 63) == 0) r[tid >> 6] = s;
    __syncthreads();
    if (tid == 0) {
        double t = 0.0;
        #pragma unroll
        for (int i = 0; i < 12; ++i) t += r[i];
        out[0] = (float)(t / (double)N);
    }
}

extern "C" void kernel_launch(void* const* d_in, const int* in_sizes, int n_in,
                              void* d_out, int out_size, void* d_ws, size_t ws_size,
                              hipStream_t stream) {
    const float* x1 = (const float*)d_in[0];
    const float* x2 = (const float*)d_in[1];

    char* ws = (char*)d_ws;
    const size_t MBYTES = (size_t)N * D;                  // 2 MiB per fp8 matrix
    unsigned* x1q = (unsigned*)(ws);
    unsigned* x2q = (unsigned*)(ws + MBYTES);
    unsigned* pq  = (unsigned*)(ws + 2 * MBYTES);
    float* sq1 = (float*)(ws + 3 * MBYTES);
    float* sq2 = (float*)(ws + 3 * MBYTES + (size_t)N * 4);
    float* sqp = (float*)(ws + 3 * MBYTES + (size_t)N * 8);
    float* partials = (float*)(ws + 3 * MBYTES + (size_t)N * 12);

    prep_kernel<<<N / 4, 256, 0, stream>>>(x1, x2, x1q, x2q, pq, sq1, sq2, sqp);
    mqjs_main<<<dim3(GJ, GI, 3), 256, 0, stream>>>(
        (const unsigned char*)x1q, (const unsigned char*)x2q, (const unsigned char*)pq,
        sq1, sq2, sqp, partials);
    finalize_kernel<<<1, 768, 0, stream>>>(partials, (float*)d_out);
}